// Round 2
// baseline (817.237 us; speedup 1.0000x reference)
//
#include <hip/hip_runtime.h>

// One thread per (b,c) column. State carried in registers across the L-layer
// sequential scan. Software-pipelined: layer l+1 inputs load while layer l
// computes. Memory-bound kernel (~1.01 GB traffic, floor ~160us @ 6.3 TB/s).

typedef float v4f __attribute__((ext_vector_type(4)));

struct LayerIn {
    float t_d, t_df;
    float e_t_d, e_r_d, e_a_d;
    float e_t_df, e_r_df, e_a_df;
};

__device__ __forceinline__ LayerIn load_layer(const float* __restrict__ pt_d,
                                              const float* __restrict__ pt_df,
                                              const float* __restrict__ pes_d,
                                              const float* __restrict__ pes_df) {
    LayerIn in;
    in.t_d    = __builtin_nontemporal_load(pt_d);
    in.t_df   = __builtin_nontemporal_load(pt_df);
    in.e_t_d  = __builtin_nontemporal_load(pes_d + 0);
    in.e_r_d  = __builtin_nontemporal_load(pes_d + 1);
    in.e_a_d  = __builtin_nontemporal_load(pes_d + 2);
    in.e_t_df = __builtin_nontemporal_load(pes_df + 0);
    in.e_r_df = __builtin_nontemporal_load(pes_df + 1);
    in.e_a_df = __builtin_nontemporal_load(pes_df + 2);
    return in;
}

__global__ __launch_bounds__(256) void upward_prop_kernel(
    const float* __restrict__ t_direct,     // (L, BC)
    const float* __restrict__ t_diffuse,    // (L, BC)
    const float* __restrict__ es_direct,    // (L, BC, 3)
    const float* __restrict__ es_diffuse,   // (L, BC, 3)
    const float* __restrict__ r_b_d_in,     // (BC)
    const float* __restrict__ r_b_df_in,    // (BC)
    const float* __restrict__ a_b_d_in,     // (BC)
    const float* __restrict__ a_b_df_in,    // (BC)
    float* __restrict__ out,                // (L, BC, 8)
    int L, int BC)
{
    const int tid = blockIdx.x * blockDim.x + threadIdx.x;
    if (tid >= BC) return;

    float r_b_d  = r_b_d_in[tid];
    float r_b_df = r_b_df_in[tid];
    float a_b_d  = a_b_d_in[tid];
    float a_b_df = a_b_df_in[tid];

    const float* pt_d   = t_direct  + tid;
    const float* pt_df  = t_diffuse + tid;
    const float* pes_d  = es_direct  + (size_t)tid * 3;
    const float* pes_df = es_diffuse + (size_t)tid * 3;
    float*       pout   = out        + (size_t)tid * 8;

    const size_t strideT  = (size_t)BC;
    const size_t strideES = (size_t)BC * 3;
    const size_t strideO  = (size_t)BC * 8;

    // Prologue: load layer 0
    LayerIn cur = load_layer(pt_d, pt_df, pes_d, pes_df);

    for (int l = 0; l < L; ++l) {
        // Issue next layer's loads early (independent of state chain)
        LayerIn nxt;
        if (l + 1 < L) {
            nxt = load_layer(pt_d  + (size_t)(l + 1) * strideT,
                             pt_df + (size_t)(l + 1) * strideT,
                             pes_d  + (size_t)(l + 1) * strideES,
                             pes_df + (size_t)(l + 1) * strideES);
        }

        const float t_d    = cur.t_d;
        const float t_df   = cur.t_df;
        const float e_t_d  = cur.e_t_d,  e_r_d  = cur.e_r_d,  e_a_d  = cur.e_a_d;
        const float e_t_df = cur.e_t_df, e_r_df = cur.e_r_df, e_a_df = cur.e_a_df;

        const float e_d  = 1.0f - t_d;
        const float e_df = 1.0f - t_df;
        const float d    = 1.0f / (1.0f - e_df * e_r_df * r_b_df);

        // direct
        const float t_m_d  = t_d * r_b_d * e_df * e_r_df * d + e_d * e_t_d * d;
        const float a_bm_d = t_d * a_b_d + t_m_d * a_b_df;
        const float r_bm_d = t_d * r_b_d * d + e_d * e_t_d * r_b_df * d;
        const float a_tm_d = e_d * e_a_d + r_bm_d * e_df * e_a_df;
        const float tdf_term = t_df + e_df * e_t_df;
        const float r_m_d  = e_d * e_r_d + r_bm_d * tdf_term;

        // diffuse
        const float t_m_df  = t_df * r_b_df * e_df * e_r_df * d + e_df * e_t_df * d;
        const float a_bm_df = t_df * a_b_df + t_m_df * a_b_df;
        const float r_bm_df = t_df * r_b_df * d + e_df * e_t_df * r_b_df * d;
        const float a_tm_df = e_df * e_a_df + r_bm_df * e_df * e_a_df;
        const float r_m_df  = e_df * e_r_df + r_bm_df * tdf_term;

        // out stack order: t_m_d, t_m_df, r_bm_d, r_bm_df, a_tm_d, a_tm_df, a_bm_d, a_bm_df
        float* po = pout + (size_t)l * strideO;
        v4f o0 = { t_m_d, t_m_df, r_bm_d, r_bm_df };
        v4f o1 = { a_tm_d, a_tm_df, a_bm_d, a_bm_df };
        __builtin_nontemporal_store(o0, (v4f*)po);
        __builtin_nontemporal_store(o1, (v4f*)(po + 4));

        // state update
        r_b_d  = r_m_d;
        r_b_df = r_m_df;
        a_b_d  = a_tm_d;
        a_b_df = a_tm_df;

        cur = nxt;
    }
}

extern "C" void kernel_launch(void* const* d_in, const int* in_sizes, int n_in,
                              void* d_out, int out_size, void* d_ws, size_t ws_size,
                              hipStream_t stream) {
    const float* t_direct   = (const float*)d_in[0];
    const float* t_diffuse  = (const float*)d_in[1];
    const float* es_direct  = (const float*)d_in[2];
    const float* es_diffuse = (const float*)d_in[3];
    const float* r_b_d      = (const float*)d_in[4];
    const float* r_b_df     = (const float*)d_in[5];
    const float* a_b_d      = (const float*)d_in[6];
    const float* a_b_df     = (const float*)d_in[7];
    float* out = (float*)d_out;

    const int BC = in_sizes[4];            // B*C from r_bottom_direct
    const int L  = in_sizes[0] / BC;       // layers

    const int block = 256;
    const int grid  = (BC + block - 1) / block;
    upward_prop_kernel<<<grid, block, 0, stream>>>(
        t_direct, t_diffuse, es_direct, es_diffuse,
        r_b_d, r_b_df, a_b_d, a_b_df, out, L, BC);
}